// Round 8
// baseline (207.568 us; speedup 1.0000x reference)
//
#include <hip/hip_runtime.h>
#include <math.h>

// B=16, C=128, H=128, W=128, MODES=16, RANK=8
// ws layout (float offsets):
//   tab  @ 0      : 8 tables of 2048 floats each (see below)
//   xtop @ 16384  : (b, i, mn, {re,im})  16*128*256*2 = 1,048,576 floats
//                   NOTE: after k_mix, the first 16384 floats of this region are
//                   reused as swf (split-bf16 skip_w in MFMA A-frag order, 32768 shorts)
//   z    @ 1064960: (b, r, {re,im})      16*8*2 = 256 floats
//   otop @ 1065216: (b, o, mn, {re,im})  1,048,576 floats
//   tf   @ 2113792: split-bf16 F1 DFT table, plain layout [part][n'][k], 8192 shorts
//   t2f  @ 2117888: bf16 I2 table in frag layout [w][n'], 4096 shorts
#define TAB_OFF 0
#define XTOP_OFF 16384
#define Z_OFF (16384 + 1048576)
#define OTOP_OFF (Z_OFF + 256)
#define TF_OFF (OTOP_OFF + 1048576)
#define T2F_OFF (TF_OFF + 4096)
#define SWF_OFF XTOP_OFF   // aliases xtop, written by k_wprep AFTER k_mix

// table float offsets (each table [2048]):
//  4096  T2C  [h][m]   cos(2pi hm/128)
//  6144  T2S  [h][m]   sin(2pi hm/128)
//  8192  T2CT [m][h]   cos(2pi hm/128)
// 10240  T2ST [m][h]   sin(2pi hm/128)
// 12288  I2C  [w][n]   c_n*cos(2pi wn/128)/128   (c_0=1, else 2)
// 14336  I2NS [w][n]  -c_n*sin(2pi wn/128)/128

using bf16x8 = __attribute__((ext_vector_type(8))) short;
using s16x4  = __attribute__((ext_vector_type(4))) short;
using f32x16 = __attribute__((ext_vector_type(16))) float;

__device__ inline unsigned short bf_rnd(float v) {
  return (unsigned short)((__float_as_uint(v) + 0x8000u) >> 16);
}
__device__ inline void bf_split(float v, unsigned short& hi, unsigned short& lo) {
  unsigned u = __float_as_uint(v);
  hi = (unsigned short)(u >> 16);
  float r = v - __uint_as_float(u & 0xFFFF0000u);
  lo = (unsigned short)(__float_as_uint(r) >> 16);
}
__device__ inline bf16x8 ldfrag(const unsigned short* p) {
  s16x4 a = *(const s16x4*)p;        // ds_read_b64 (8B aligned)
  s16x4 b = *(const s16x4*)(p + 4);
  bf16x8 r;
  r[0] = a[0]; r[1] = a[1]; r[2] = a[2]; r[3] = a[3];
  r[4] = b[0]; r[5] = b[1]; r[6] = b[2]; r[7] = b[3];
  return r;
}
// swizzled frag read from a [rows][128-short] LDS tile, row stride 256 B:
// byte ^= (row&7)<<4 (same XOR applied on the write side).
__device__ inline bf16x8 ldfrag_sw(const unsigned short* base, int row, int koff) {
  int byte = row * 256 + ((koff * 2) ^ ((row & 7) << 4));
  return ldfrag((const unsigned short*)((const char*)base + byte));
}

__global__ __launch_bounds__(256) void k_tab(float* __restrict__ tab) {
  int idx = blockIdx.x * 256 + threadIdx.x;
  if (idx >= 16384) return;
  int which = idx >> 11, rem = idx & 2047;
  int a, j;
  if (which == 4 || which == 5) { a = rem & 127; j = rem >> 7; }  // [m][h]
  else { a = rem >> 4; j = rem & 15; }
  int p = (a * j) & 127;  // exact phase reduction
  float ang = (float)p * (float)(3.14159265358979323846 / 64.0);
  float cv = cosf(ang), sv = sinf(ang);
  float v;
  switch (which) {
    case 0: v = cv * (1.f / 128.f); break;
    case 1: v = -sv * (1.f / 128.f); break;
    case 2: v = cv; break;
    case 3: v = sv; break;
    case 4: v = cv; break;
    case 5: v = sv; break;
    case 6: v = ((rem & 15) == 0 ? 1.f : 2.f) * cv * (1.f / 128.f); break;
    default: v = ((rem & 15) == 0 ? 1.f : 2.f) * (-sv) * (1.f / 128.f); break;
  }
  tab[idx] = v;
}

// F1 table, split hi/lo, plain layout tf[part*4096 + n'*128 + k]:
// n'<16: cos(2pi k n'/128)/128 ; n'>=16: -sin(2pi k (n'-16)/128)/128
__global__ __launch_bounds__(256) void k_fprep(unsigned short* __restrict__ tf) {
  int idx = blockIdx.x * 256 + threadIdx.x;  // [0,4096)
  if (idx >= 4096) return;
  int np = idx >> 7, k = idx & 127;
  int n = np & 15;
  int p = (k * n) & 127;
  float ang = (float)p * (float)(3.14159265358979323846 / 64.0);
  float v = (np < 16 ? cosf(ang) : -sinf(ang)) * (1.f / 128.f);
  unsigned short hi, lo;
  bf_split(v, hi, lo);
  tf[np * 128 + k] = hi;
  tf[4096 + np * 128 + k] = lo;
}

// I2 table in B-frag layout: t2f[w*32 + n'] = bf16(I2C[w][n']) for n'<16,
// bf16(I2NS[w][n'-16]) for n'>=16. Read per lane as 16B at w*32 + kb.
__global__ __launch_bounds__(256) void k_t2prep(const float* __restrict__ tab,
                                                unsigned short* __restrict__ t2f) {
  int idx = blockIdx.x * 256 + threadIdx.x;  // [0,4096)
  if (idx >= 4096) return;
  int w = idx >> 5, np = idx & 31;
  float v = (np < 16) ? tab[12288 + w * 16 + np] : tab[14336 + w * 16 + (np - 16)];
  t2f[idx] = bf_rnd(v);
}

// Split skip_w into hi/lo bf16 and store in MFMA A-frag order:
// element k of row o (k = kc*32 + ks*16 + kh*8 + j) lands at
// swf[((kc*2+ks)*2+part)*2048 + o*16 + kh*8 + j].
__global__ __launch_bounds__(256) void k_wprep(const float* __restrict__ sw,
                                               unsigned short* __restrict__ swf) {
  int idx = blockIdx.x * 256 + threadIdx.x;
  if (idx >= 16384) return;
  int o = idx >> 7, k = idx & 127;
  unsigned short hb, lb;
  bf_split(sw[o * 128 + k], hb, lb);
  int kc = k >> 5, ks = (k >> 4) & 1, kh = (k >> 3) & 1, j = k & 7;
  int f0 = (kc * 2 + ks) * 2;
  swf[(f0 + 0) * 2048 + o * 16 + kh * 8 + j] = hb;
  swf[(f0 + 1) * 2048 + o * 16 + kh * 8 + j] = lb;
}

// Forward truncated DFT via MFMA. Block = one (b,c) image, 256 threads (4 waves).
__global__ __launch_bounds__(256) void k_fwd(const float* __restrict__ x,
                                             const unsigned short* __restrict__ tf,
                                             const float* __restrict__ tab,
                                             float* __restrict__ xtop) {
  __shared__ unsigned short Xh[128 * 128];   // [h][w] bf16, swizzled; later aliased by Ar/Ai
  __shared__ unsigned short Tfh[32 * 128];   // [n'][k] swizzled
  __shared__ unsigned short Tfl[32 * 128];
  const int c = blockIdx.x, b = blockIdx.y;
  const int t = threadIdx.x;
  const int lane = t & 63, wv = t >> 6;

  // ---- stage Tf (8192 shorts) ----
  #pragma unroll
  for (int it = 0; it < 32; ++it) {
    int idx = it * 256 + t;                  // [0,8192)
    int part = idx >> 12, rem = idx & 4095;
    int row = rem >> 7, k = rem & 127;
    unsigned short v = tf[part * 4096 + rem];
    unsigned short* dst = part ? Tfl : Tfh;
    *(unsigned short*)((char*)dst + row * 256 + ((k * 2) ^ ((row & 7) << 4))) = v;
  }
  // ---- stage x as bf16 (coalesced float4 reads) ----
  const float* img = x + (((size_t)(b * 128 + c)) << 14);
  #pragma unroll
  for (int it = 0; it < 16; ++it) {
    int flat = it * 256 + t;                 // [0,4096)
    int h = flat >> 5, wq = flat & 31;
    float4 v = *(const float4*)(img + (size_t)flat * 4);
    s16x4 pk;
    pk[0] = (short)bf_rnd(v.x); pk[1] = (short)bf_rnd(v.y);
    pk[2] = (short)bf_rnd(v.z); pk[3] = (short)bf_rnd(v.w);
    *(s16x4*)((char*)Xh + h * 256 + ((wq * 8) ^ ((h & 7) << 4))) = pk;
  }
  __syncthreads();

  // ---- F1 MFMA: wave wv owns h-rows [wv*32, wv*32+32) ----
  f32x16 acc;
  #pragma unroll
  for (int e = 0; e < 16; ++e) acc[e] = 0.f;
  const int orow = wv * 32 + (lane & 31);
  const int bcol = lane & 31;
  const int kh8 = (lane >> 5) * 8;
  #pragma unroll
  for (int kc8 = 0; kc8 < 8; ++kc8) {        // 8 k-steps of 16
    int kfull = kc8 * 16 + kh8;
    bf16x8 a  = ldfrag_sw(Xh, orow, kfull);
    bf16x8 th = ldfrag_sw(Tfh, bcol, kfull);
    bf16x8 tl = ldfrag_sw(Tfl, bcol, kfull);
    acc = __builtin_amdgcn_mfma_f32_32x32x16_bf16(a, th, acc, 0, 0, 0);
    acc = __builtin_amdgcn_mfma_f32_32x32x16_bf16(a, tl, acc, 0, 0, 0);
  }
  __syncthreads();  // all frag reads of Xh done before aliasing it

  // ---- write A to transpose buffers Ar[n][h], Ai[n][h] (alias Xh region) ----
  float* Arp = (float*)Xh;          // [16][132]
  float* Aip = Arp + 16 * 132;      // [16][132]; total 16896 B <= 32768 B
  {
    const int col = lane & 31;
    #pragma unroll
    for (int r = 0; r < 16; ++r) {
      int h = wv * 32 + (r & 3) + 8 * (r >> 2) + 4 * (lane >> 5);
      if (col < 16) Arp[col * 132 + h] = acc[r];
      else          Aip[(col - 16) * 132 + h] = acc[r];
    }
  }
  __syncthreads();

  // ---- F2 (fp32): thread t -> (m = t>>4, n = t&15) ----
  {
    const int m = t >> 4, n = t & 15;
    const float* tc = tab + 8192 + m * 128;   // T2CT[m][h]
    const float* ts = tab + 10240 + m * 128;  // T2ST[m][h]
    const float* ar = Arp + n * 132;
    const float* ai = Aip + n * 132;
    float xr = 0.f, xi = 0.f;
    #pragma unroll 8
    for (int h4 = 0; h4 < 128; h4 += 4) {
      float4 av = *(const float4*)(ar + h4);
      float4 iv = *(const float4*)(ai + h4);
      float4 cv = *(const float4*)(tc + h4);
      float4 sv = *(const float4*)(ts + h4);
      xr += av.x * cv.x + iv.x * sv.x;  xi += iv.x * cv.x - av.x * sv.x;
      xr += av.y * cv.y + iv.y * sv.y;  xi += iv.y * cv.y - av.y * sv.y;
      xr += av.z * cv.z + iv.z * sv.z;  xi += iv.z * cv.z - av.z * sv.z;
      xr += av.w * cv.w + iv.w * sv.w;  xi += iv.w * cv.w - av.w * sv.w;
    }
    size_t base = ((size_t)(b * 128 + c)) * 512 + (size_t)(m * 16 + n) * 2;
    xtop[base] = xr; xtop[base + 1] = xi;
  }
}

// z[b,r] += partial over i-chunk; z zeroed by memset beforehand.
__global__ __launch_bounds__(256) void k_z(const float* __restrict__ xtop,
                                           const float* __restrict__ vre,
                                           const float* __restrict__ vim,
                                           float* __restrict__ zout) {
  int b = blockIdx.x, ic = blockIdx.y, t = threadIdx.x;
  float zr[8], zi[8];
  #pragma unroll
  for (int r = 0; r < 8; ++r) { zr[r] = 0.f; zi[r] = 0.f; }
  const float* xb = xtop + ((size_t)b * 128) * 512;
  for (int i = ic * 16; i < ic * 16 + 16; ++i) {
    float xr = xb[i * 512 + t * 2], xi = xb[i * 512 + t * 2 + 1];
    #pragma unroll
    for (int r = 0; r < 8; ++r) {
      float vr = vre[(size_t)(i * 8 + r) * 256 + t];
      float vi = vim[(size_t)(i * 8 + r) * 256 + t];
      zr[r] += xr * vr + xi * vi;
      zi[r] += xi * vr - xr * vi;
    }
  }
  #pragma unroll
  for (int r = 0; r < 8; ++r)
    for (int off = 32; off > 0; off >>= 1) {
      zr[r] += __shfl_down(zr[r], off);
      zi[r] += __shfl_down(zi[r], off);
    }
  __shared__ float red[4][16];
  int wid = t >> 6, lane = t & 63;
  if (lane == 0) {
    #pragma unroll
    for (int r = 0; r < 8; ++r) { red[wid][r * 2] = zr[r]; red[wid][r * 2 + 1] = zi[r]; }
  }
  __syncthreads();
  if (t < 16) atomicAdd(&zout[b * 16 + t], red[0][t] + red[1][t] + red[2][t] + red[3][t]);
}

// otop[b,o,mn] += partial over i-chunk (+ U z term from ic==0 chunk).
__global__ __launch_bounds__(256) void k_mix(const float* __restrict__ xtop,
                                             const float* __restrict__ wre,
                                             const float* __restrict__ wim,
                                             const float* __restrict__ ure,
                                             const float* __restrict__ uim,
                                             const float* __restrict__ z,
                                             float* __restrict__ otop) {
  int o0 = blockIdx.x * 4, b0 = blockIdx.y * 2, ic = blockIdx.z, t = threadIdx.x;
  float ar[2][4], ai[2][4];
  #pragma unroll
  for (int bb = 0; bb < 2; ++bb)
    #pragma unroll
    for (int oo = 0; oo < 4; ++oo) { ar[bb][oo] = 0.f; ai[bb][oo] = 0.f; }
  const float* x0 = xtop + ((size_t)(b0 * 128)) * 512;
  const float* x1 = x0 + 128 * 512;
  for (int i = ic * 16; i < ic * 16 + 16; ++i) {
    float x0r = x0[i * 512 + t * 2], x0i = x0[i * 512 + t * 2 + 1];
    float x1r = x1[i * 512 + t * 2], x1i = x1[i * 512 + t * 2 + 1];
    #pragma unroll
    for (int oo = 0; oo < 4; ++oo) {
      size_t di = (size_t)((o0 + oo) * 128 + i) * 256 + t;
      float dr = wre[di], dj = wim[di];
      ar[0][oo] += dr * x0r - dj * x0i; ai[0][oo] += dr * x0i + dj * x0r;
      ar[1][oo] += dr * x1r - dj * x1i; ai[1][oo] += dr * x1i + dj * x1r;
    }
  }
  if (ic == 0) {
    float zr[2][8], zi[2][8];
    #pragma unroll
    for (int bb = 0; bb < 2; ++bb)
      #pragma unroll
      for (int r = 0; r < 8; ++r) {
        zr[bb][r] = z[(b0 + bb) * 16 + r * 2];
        zi[bb][r] = z[(b0 + bb) * 16 + r * 2 + 1];
      }
    #pragma unroll
    for (int oo = 0; oo < 4; ++oo)
      #pragma unroll
      for (int r = 0; r < 8; ++r) {
        float urv = ure[(size_t)((o0 + oo) * 8 + r) * 256 + t];
        float uiv = uim[(size_t)((o0 + oo) * 8 + r) * 256 + t];
        #pragma unroll
        for (int bb = 0; bb < 2; ++bb) {
          ar[bb][oo] += urv * zr[bb][r] - uiv * zi[bb][r];
          ai[bb][oo] += urv * zi[bb][r] + uiv * zr[bb][r];
        }
      }
  }
  #pragma unroll
  for (int bb = 0; bb < 2; ++bb)
    #pragma unroll
    for (int oo = 0; oo < 4; ++oo) {
      size_t oi = ((size_t)((b0 + bb) * 128 + o0 + oo) * 256 + (size_t)t) * 2;
      atomicAdd(&otop[oi], ar[bb][oo]);
      atomicAdd(&otop[oi + 1], ai[bb][oo]);
    }
}

// Fused inverse-DFT + skip-GEMM + activation.
// Block = (h, b). NEW decomposition: wave wv owns ALL 128 o-rows x 32 w-cols
// (w = wv*32 .. wv*32+31). B-frags (x) are built directly in registers from
// global (two 128B segments per load instr) — no LDS staging, no main-loop
// barriers. A-frags from swf (round-7 verified). I2 table from t2f (global,
// frag layout). Only LDS: Ylds (9 KB) + one barrier after I1.
__global__ __launch_bounds__(256) void k_out(const float* __restrict__ x,
                                             const unsigned short* __restrict__ swf,
                                             const unsigned short* __restrict__ t2f,
                                             const float* __restrict__ otop,
                                             const float* __restrict__ tab,
                                             float* __restrict__ out) {
  __shared__ unsigned short Ylds[128 * 36];  // [o][k]: k<16 Yr[n], k>=16 Yi[n]
  const int h = blockIdx.x, b = blockIdx.y;
  const int t = threadIdx.x;
  const int lane = t & 63, wv = t >> 6;
  const int kh8 = (lane >> 5) * 8;
  const int col = lane & 31;
  const int w0 = wv * 32;

  // ---- I1: Y[o][n] = sum_m X[o][m][n] e^{+2pi i m h/128} (fp32) ----
  {
    int o = t >> 1, nh = (t & 1) * 8;
    float yr[8], yi[8];
    #pragma unroll
    for (int j = 0; j < 8; ++j) { yr[j] = 0.f; yi[j] = 0.f; }
    const float* xb = otop + ((size_t)(b * 128 + o)) * 512 + nh * 2;
    #pragma unroll 4
    for (int m = 0; m < 16; ++m) {
      float cm = tab[4096 + h * 16 + m];   // uniform -> s_load
      float sm = tab[6144 + h * 16 + m];
      float4 q0 = *(const float4*)(xb + m * 32 + 0);
      float4 q1 = *(const float4*)(xb + m * 32 + 4);
      float4 q2 = *(const float4*)(xb + m * 32 + 8);
      float4 q3 = *(const float4*)(xb + m * 32 + 12);
      yr[0] += q0.x * cm - q0.y * sm; yi[0] += q0.x * sm + q0.y * cm;
      yr[1] += q0.z * cm - q0.w * sm; yi[1] += q0.z * sm + q0.w * cm;
      yr[2] += q1.x * cm - q1.y * sm; yi[2] += q1.x * sm + q1.y * cm;
      yr[3] += q1.z * cm - q1.w * sm; yi[3] += q1.z * sm + q1.w * cm;
      yr[4] += q2.x * cm - q2.y * sm; yi[4] += q2.x * sm + q2.y * cm;
      yr[5] += q2.z * cm - q2.w * sm; yi[5] += q2.z * sm + q2.w * cm;
      yr[6] += q3.x * cm - q3.y * sm; yi[6] += q3.x * sm + q3.y * cm;
      yr[7] += q3.z * cm - q3.w * sm; yi[7] += q3.z * sm + q3.w * cm;
    }
    #pragma unroll
    for (int j = 0; j < 8; ++j) {
      Ylds[o * 36 + nh + j] = bf_rnd(yr[j]);
      Ylds[o * 36 + 16 + nh + j] = bf_rnd(yi[j]);
    }
  }
  __syncthreads();

  f32x16 acc[4];
  #pragma unroll
  for (int ot = 0; ot < 4; ++ot)
    #pragma unroll
    for (int e = 0; e < 16; ++e) acc[ot][e] = 0.f;

  // ---- skip GEMM: 8 k-steps of 16, zero barriers ----
  const float* xb = x + (size_t)b * 2097152 + (size_t)h * 128 + (w0 + col);
  #pragma unroll
  for (int ks8 = 0; ks8 < 8; ++ks8) {
    const int c0 = ks8 * 16 + kh8;
    float xd[8];
    #pragma unroll
    for (int j = 0; j < 8; ++j) xd[j] = xb[(size_t)(c0 + j) * 16384];
    bf16x8 bh, bl;
    #pragma unroll
    for (int j = 0; j < 8; ++j) {
      unsigned short hb, lb;
      bf_split(xd[j], hb, lb);
      bh[j] = (short)hb; bl[j] = (short)lb;
    }
    const unsigned short* abase = swf + ks8 * 4096 + kh8;  // + part*2048 + o*16
    #pragma unroll
    for (int ot = 0; ot < 4; ++ot) {
      const int o = ot * 32 + col;
      bf16x8 ah = *(const bf16x8*)(abase + o * 16);
      bf16x8 al = *(const bf16x8*)(abase + 2048 + o * 16);
      acc[ot] = __builtin_amdgcn_mfma_f32_32x32x16_bf16(ah, bh, acc[ot], 0, 0, 0);
      acc[ot] = __builtin_amdgcn_mfma_f32_32x32x16_bf16(ah, bl, acc[ot], 0, 0, 0);
      acc[ot] = __builtin_amdgcn_mfma_f32_32x32x16_bf16(al, bh, acc[ot], 0, 0, 0);
    }
  }

  // ---- S2: spectral I2 via MFMA into the same accumulators ----
  #pragma unroll
  for (int ks = 0; ks < 2; ++ks) {
    const int kb = ks * 16 + kh8;
    bf16x8 tb = *(const bf16x8*)(t2f + (w0 + col) * 32 + kb);
    #pragma unroll
    for (int ot = 0; ot < 4; ++ot) {
      bf16x8 ya = ldfrag(&Ylds[(ot * 32 + col) * 36 + kb]);
      acc[ot] = __builtin_amdgcn_mfma_f32_32x32x16_bf16(ya, tb, acc[ot], 0, 0, 0);
    }
  }

  // ---- epilogue: activation + store ----
  #pragma unroll
  for (int ot = 0; ot < 4; ++ot) {
    #pragma unroll
    for (int r = 0; r < 16; ++r) {
      int o = ot * 32 + (r & 3) + 8 * (r >> 2) + 4 * (lane >> 5);
      float v = acc[ot][r];
      out[((size_t)(b * 128 + o)) * 16384 + (size_t)h * 128 + w0 + col] = v * __expf(-v * v);
    }
  }
}

extern "C" void kernel_launch(void* const* d_in, const int* in_sizes, int n_in,
                              void* d_out, int out_size, void* d_ws, size_t ws_size,
                              hipStream_t stream) {
  const float* x  = (const float*)d_in[0];
  const float* wr = (const float*)d_in[1];
  const float* wi = (const float*)d_in[2];
  const float* ur = (const float*)d_in[3];
  const float* ui = (const float*)d_in[4];
  const float* vr = (const float*)d_in[5];
  const float* vi = (const float*)d_in[6];
  const float* sw = (const float*)d_in[7];
  float* out  = (float*)d_out;
  float* ws   = (float*)d_ws;
  float* tab  = ws + TAB_OFF;
  float* xtop = ws + XTOP_OFF;
  float* z    = ws + Z_OFF;
  float* otop = ws + OTOP_OFF;
  unsigned short* tf  = (unsigned short*)(ws + TF_OFF);
  unsigned short* t2f = (unsigned short*)(ws + T2F_OFF);
  unsigned short* swf = (unsigned short*)(ws + SWF_OFF);  // aliases xtop (dead after k_mix)

  hipMemsetAsync(z, 0, 256 * sizeof(float), stream);
  hipMemsetAsync(otop, 0, 1048576 * sizeof(float), stream);
  hipLaunchKernelGGL(k_tab, dim3(64), dim3(256), 0, stream, tab);
  hipLaunchKernelGGL(k_fprep, dim3(16), dim3(256), 0, stream, tf);
  hipLaunchKernelGGL(k_t2prep, dim3(16), dim3(256), 0, stream, tab, t2f);
  hipLaunchKernelGGL(k_fwd, dim3(128, 16), dim3(256), 0, stream, x, tf, tab, xtop);
  hipLaunchKernelGGL(k_z,   dim3(16, 8), dim3(256), 0, stream, xtop, vr, vi, z);
  hipLaunchKernelGGL(k_mix, dim3(32, 8, 8), dim3(256), 0, stream, xtop, wr, wi, ur, ui, z, otop);
  hipLaunchKernelGGL(k_wprep, dim3(64), dim3(256), 0, stream, sw, swf);  // after k_mix: xtop is dead
  hipLaunchKernelGGL(k_out, dim3(128, 16), dim3(256), 0, stream, x, swf, t2f, otop, tab, out);
}